// Round 1
// baseline (553.639 us; speedup 1.0000x reference)
//
#include <hip/hip_runtime.h>

#define E 1024
#define KK 20
#define NOUT 40980      // KK*(2*E+1)
#define VLOC 20500      // KK + KK*E
#define SROW (2*NOUT)   // 81960
#define TILE 64
#define PAD 21

// ws layout (floats): [0]=num, [1]=den, [2]=objU_sum, [3]=objV_sum
__global__ void init_ws_kernel(float* ws) {
    int t = threadIdx.x;
    if (t < 4) ws[t] = 0.0f;
}

// One block per (batch, {U,V}). Computes sum_{j<k} |sum_e M[e,j]*M[e,k]| (complex, no conj).
__global__ __launch_bounds__(256) void obj_kernel(const float* __restrict__ nn,
                                                  float* __restrict__ ws) {
    const int CH = 512;
    __shared__ float2 sM[CH * PAD];
    __shared__ float red[256];
    int bb = blockIdx.x;
    int b = bb >> 1, which = bb & 1;
    const float* baseR = nn + (size_t)b * SROW + (which ? VLOC : KK);
    const float* baseI = baseR + NOUT;
    int t = threadIdx.x;

    // map thread -> strict-upper pair (j, kq), 190 pairs for K=20
    int j = 0, kq = 0;
    if (t < 190) {
        int p = t, jj = 0, cnt = KK - 1;
        while (p >= cnt) { p -= cnt; jj++; cnt--; }
        j = jj; kq = jj + 1 + p;
    }

    float gr = 0.f, gi = 0.f;
    for (int e0 = 0; e0 < E; e0 += CH) {
        __syncthreads();
        for (int idx = t; idx < CH * KK; idx += 256) {
            int dst = idx + idx / KK;   // row pad 20 -> 21
            sM[dst] = make_float2(baseR[e0 * KK + idx], baseI[e0 * KK + idx]);
        }
        __syncthreads();
        if (t < 190) {
            #pragma unroll 4
            for (int e = 0; e < CH; e++) {
                float2 a = sM[e * PAD + j];
                float2 c2 = sM[e * PAD + kq];
                gr += a.x * c2.x - a.y * c2.y;
                gi += a.x * c2.y + a.y * c2.x;
            }
        }
    }
    float mag = (t < 190) ? sqrtf(gr * gr + gi * gi) : 0.f;
    __syncthreads();
    red[t] = mag;
    __syncthreads();
    for (int s = 128; s > 0; s >>= 1) {
        if (t < s) red[t] += red[t + s];
        __syncthreads();
    }
    if (t == 0) atomicAdd(&ws[2 + which], red[0]);
}

// Grid (E/TILE, E/TILE, B). Each block: 64x64 (e,f) tile of pred vs kern.
__global__ __launch_bounds__(256) void main_kernel(const float* __restrict__ nn,
                                                   const float* __restrict__ krn_r,
                                                   const float* __restrict__ krn_i,
                                                   float* __restrict__ ws) {
    __shared__ float2 sW[TILE * PAD];  // W = U*d, rows = local e, pad 21
    __shared__ float2 sV[TILE * PAD];  // rows = local f
    __shared__ float redN[256], redD[256];
    int b = blockIdx.z;
    int e0 = blockIdx.y * TILE;
    int f0 = blockIdx.x * TILE;
    const float* nb = nn + (size_t)b * SROW;
    int t = threadIdx.x;

    // stage: W[e_local][k] = U[e0+e_local][k] * d[k] (complex); V straight copy
    for (int idx = t; idx < TILE * KK; idx += 256) {
        int k = idx % KK;
        int dst = idx + idx / KK;
        float dr = nb[k], di = nb[NOUT + k];
        float ur = nb[KK + e0 * KK + idx];
        float ui = nb[NOUT + KK + e0 * KK + idx];
        sW[dst] = make_float2(ur * dr - ui * di, ur * di + ui * dr);
        sV[dst] = make_float2(nb[VLOC + f0 * KK + idx], nb[NOUT + VLOC + f0 * KK + idx]);
    }
    __syncthreads();

    int fe = (t & 15) * 4;   // local f base (4 contiguous f per thread -> float4 kern loads)
    int te = (t >> 4) * 4;   // local e base
    float pr[4][4] = {{0.f}}, pi[4][4] = {{0.f}};
    #pragma unroll
    for (int k = 0; k < KK; k++) {
        float2 w[4], v[4];
        #pragma unroll
        for (int i = 0; i < 4; i++) w[i] = sW[(te + i) * PAD + k];
        #pragma unroll
        for (int j2 = 0; j2 < 4; j2++) v[j2] = sV[(fe + j2) * PAD + k];
        #pragma unroll
        for (int i = 0; i < 4; i++)
            #pragma unroll
            for (int j2 = 0; j2 < 4; j2++) {
                pr[i][j2] += w[i].x * v[j2].x - w[i].y * v[j2].y;
                pi[i][j2] += w[i].x * v[j2].y + w[i].y * v[j2].x;
            }
    }

    float num = 0.f, den = 0.f;
    size_t base = ((size_t)b * E + (size_t)(e0 + te)) * E + (size_t)(f0 + fe);
    #pragma unroll
    for (int i = 0; i < 4; i++) {
        float4 a = *(const float4*)(krn_r + base + (size_t)i * E);
        float4 c4 = *(const float4*)(krn_i + base + (size_t)i * E);
        float ar[4] = {a.x, a.y, a.z, a.w};
        float ai2[4] = {c4.x, c4.y, c4.z, c4.w};
        #pragma unroll
        for (int j2 = 0; j2 < 4; j2++) {
            float drr = ar[j2] - pr[i][j2];
            float dii = ai2[j2] - pi[i][j2];
            num += drr * drr + dii * dii;
            den += ar[j2] * ar[j2] + ai2[j2] * ai2[j2];
        }
    }

    redN[t] = num; redD[t] = den;
    __syncthreads();
    for (int s = 128; s > 0; s >>= 1) {
        if (t < s) { redN[t] += redN[t + s]; redD[t] += redD[t + s]; }
        __syncthreads();
    }
    if (t == 0) {
        atomicAdd(&ws[0], redN[0]);
        atomicAdd(&ws[1], redD[0]);
    }
}

__global__ void fin_kernel(const float* __restrict__ ws, const int* __restrict__ bsz,
                           float* __restrict__ out) {
    if (threadIdx.x == 0 && blockIdx.x == 0) {
        float Bf = (float)bsz[0];
        float obj1 = ws[2] / Bf;
        float obj2 = ws[3] / Bf;
        out[0] = ws[0] / ws[1] + 0.01f * (obj1 + obj2);
        out[1] = obj1;
        out[2] = obj2;
    }
}

extern "C" void kernel_launch(void* const* d_in, const int* in_sizes, int n_in,
                              void* d_out, int out_size, void* d_ws, size_t ws_size,
                              hipStream_t stream) {
    const float* nn = (const float*)d_in[0];
    const float* kr = (const float*)d_in[1];
    const float* ki = (const float*)d_in[2];
    const int* bsz = (const int*)d_in[3];
    float* ws = (float*)d_ws;
    float* out = (float*)d_out;
    int B = in_sizes[0] / SROW;

    hipLaunchKernelGGL(init_ws_kernel, dim3(1), dim3(64), 0, stream, ws);
    hipLaunchKernelGGL(obj_kernel, dim3(2 * B), dim3(256), 0, stream, nn, ws);
    hipLaunchKernelGGL(main_kernel, dim3(E / TILE, E / TILE, B), dim3(256), 0, stream,
                       nn, kr, ki, ws);
    hipLaunchKernelGGL(fin_kernel, dim3(1), dim3(64), 0, stream, ws, bsz, out);
}

// Round 2
// 441.109 us; speedup vs baseline: 1.2551x; 1.2551x over previous
//
#include <hip/hip_runtime.h>

#define E 1024
#define KK 20
#define NOUT 40980      // KK*(2*E+1)
#define VLOC 20500      // KK + KK*E
#define SROW (2*NOUT)   // 81960
#define TILE 64
#define ROWF2 72        // float2 stride per k-row in LDS (64 + 4 group pads of 2)
#define GOFF 16         // ws float offset of Gram partials
#define NPAIR 190       // K*(K-1)/2

// ws layout (floats): [0]=num, [1]=den, [2]=objU, [3]=objV, [16..16+B*2*190*2) Gram partials
__global__ void init_ws_kernel(float* ws, int n) {
    int i = blockIdx.x * blockDim.x + threadIdx.x;
    if (i < n) ws[i] = 0.0f;
}

__device__ __forceinline__ int swz(int e) { return e + ((e >> 4) << 1); }

// ---------------- Gram partials: 512 blocks = B * 2 * 8 e-chunks ----------------
__global__ __launch_bounds__(256) void gram_kernel(const float* __restrict__ nn,
                                                   float* __restrict__ ws) {
    const int CH = 128;
    __shared__ float2 sM[CH * 21];
    int bx = blockIdx.x;
    int chunk = bx & 7, which = (bx >> 3) & 1, b = bx >> 4;
    const float* baseR = nn + (size_t)b * SROW + (which ? VLOC : KK) + chunk * CH * KK;
    const float* baseI = baseR + NOUT;
    int t = threadIdx.x;
    for (int idx = t; idx < CH * KK; idx += 256) {
        int dst = idx + idx / KK;           // pad row 20 -> 21 float2
        sM[dst] = make_float2(baseR[idx], baseI[idx]);
    }
    __syncthreads();
    if (t < NPAIR) {
        int p = t, j = 0, cnt = KK - 1;
        while (p >= cnt) { p -= cnt; j++; cnt--; }
        int kq = j + 1 + p;
        float gr = 0.f, gi = 0.f;
        #pragma unroll 8
        for (int e = 0; e < CH; e++) {
            float2 a = sM[e * 21 + j];
            float2 c = sM[e * 21 + kq];
            gr += a.x * c.x - a.y * c.y;
            gi += a.x * c.y + a.y * c.x;
        }
        int go = GOFF + (((b * 2 + which) * NPAIR) + t) * 2;
        atomicAdd(&ws[go], gr);
        atomicAdd(&ws[go + 1], gi);
    }
}

// ---------------- abs + reduce: 64 blocks = B * 2 ----------------
__global__ __launch_bounds__(256) void absred_kernel(float* __restrict__ ws) {
    __shared__ float red[4];
    int bw = blockIdx.x;      // b*2 + which
    int t = threadIdx.x;
    float m = 0.f;
    if (t < NPAIR) {
        int go = GOFF + (bw * NPAIR + t) * 2;
        float gr = ws[go], gi = ws[go + 1];
        m = sqrtf(gr * gr + gi * gi);
    }
    #pragma unroll
    for (int off = 32; off > 0; off >>= 1) m += __shfl_down(m, off, 64);
    if ((t & 63) == 0) red[t >> 6] = m;
    __syncthreads();
    if (t == 0) atomicAdd(&ws[2 + (bw & 1)], red[0] + red[1] + red[2] + red[3]);
}

// ---------------- main: grid (16,16,B), 64x64 tile, 4x4 complex per thread ----------------
__global__ __launch_bounds__(256) void main_kernel(const float* __restrict__ nn,
                                                   const float* __restrict__ krn_r,
                                                   const float* __restrict__ krn_i,
                                                   float* __restrict__ ws) {
    __shared__ __align__(16) float2 sW[KK * ROWF2];   // [k][e_local swizzled]
    __shared__ __align__(16) float2 sV[KK * ROWF2];   // [k][f_local swizzled]
    __shared__ float redN[4], redD[4];
    int b = blockIdx.z;
    int e0 = blockIdx.y * TILE;
    int f0 = blockIdx.x * TILE;
    const float* nb = nn + (size_t)b * SROW;
    int t = threadIdx.x;
    int fe = (t & 15) * 4;
    int te = (t >> 4) * 4;

    // Early prefetch of the kern tile (no deps; hides HBM latency under the FMA loop)
    size_t base = ((size_t)b * E + (size_t)(e0 + te)) * E + (size_t)(f0 + fe);
    float4 tr[4], ti[4];
    #pragma unroll
    for (int i = 0; i < 4; i++) {
        tr[i] = *(const float4*)(krn_r + base + (size_t)i * E);
        ti[i] = *(const float4*)(krn_i + base + (size_t)i * E);
    }

    // Stage W = U*d and V into [k][row] LDS; e fastest -> wave-uniform k (scalar d loads),
    // swizzled dst -> ~2-way write conflicts only.
    for (int idx = t; idx < TILE * KK; idx += 256) {
        int e = idx & 63, k = idx >> 6;
        float dr = nb[k], di = nb[NOUT + k];
        float ur = nb[KK + (size_t)(e0 + e) * KK + k];
        float ui = nb[NOUT + KK + (size_t)(e0 + e) * KK + k];
        float vr = nb[VLOC + (size_t)(f0 + e) * KK + k];
        float vi = nb[NOUT + VLOC + (size_t)(f0 + e) * KK + k];
        int dst = k * ROWF2 + swz(e);
        sW[dst] = make_float2(ur * dr - ui * di, ur * di + ui * dr);
        sV[dst] = make_float2(vr, vi);
    }
    __syncthreads();

    float pr[4][4] = {{0.f}}, pi[4][4] = {{0.f}};
    int wbase = swz(te);   // te%16 in {0,4,8,12} -> swz(te..te+3) contiguous, 16B-aligned
    int vbase = swz(fe);
    #pragma unroll
    for (int k = 0; k < KK; k++) {
        const float4* wp = (const float4*)&sW[k * ROWF2 + wbase];
        const float4* vp = (const float4*)&sV[k * ROWF2 + vbase];
        float4 wa = wp[0], wb = wp[1];
        float4 va = vp[0], vb = vp[1];
        float2 w[4] = {{wa.x, wa.y}, {wa.z, wa.w}, {wb.x, wb.y}, {wb.z, wb.w}};
        float2 v[4] = {{va.x, va.y}, {va.z, va.w}, {vb.x, vb.y}, {vb.z, vb.w}};
        #pragma unroll
        for (int i = 0; i < 4; i++)
            #pragma unroll
            for (int j = 0; j < 4; j++) {
                pr[i][j] += w[i].x * v[j].x - w[i].y * v[j].y;
                pi[i][j] += w[i].x * v[j].y + w[i].y * v[j].x;
            }
    }

    float num = 0.f, den = 0.f;
    #pragma unroll
    for (int i = 0; i < 4; i++) {
        float ar[4] = {tr[i].x, tr[i].y, tr[i].z, tr[i].w};
        float ai[4] = {ti[i].x, ti[i].y, ti[i].z, ti[i].w};
        #pragma unroll
        for (int j = 0; j < 4; j++) {
            float dr = ar[j] - pr[i][j];
            float di = ai[j] - pi[i][j];
            num += dr * dr + di * di;
            den += ar[j] * ar[j] + ai[j] * ai[j];
        }
    }

    #pragma unroll
    for (int off = 32; off > 0; off >>= 1) {
        num += __shfl_down(num, off, 64);
        den += __shfl_down(den, off, 64);
    }
    if ((t & 63) == 0) { redN[t >> 6] = num; redD[t >> 6] = den; }
    __syncthreads();
    if (t == 0) {
        atomicAdd(&ws[0], redN[0] + redN[1] + redN[2] + redN[3]);
        atomicAdd(&ws[1], redD[0] + redD[1] + redD[2] + redD[3]);
    }
}

__global__ void fin_kernel(const float* __restrict__ ws, const int* __restrict__ bsz,
                           float* __restrict__ out) {
    if (threadIdx.x == 0 && blockIdx.x == 0) {
        float Bf = (float)bsz[0];
        float obj1 = ws[2] / Bf;
        float obj2 = ws[3] / Bf;
        out[0] = ws[0] / ws[1] + 0.01f * (obj1 + obj2);
        out[1] = obj1;
        out[2] = obj2;
    }
}

extern "C" void kernel_launch(void* const* d_in, const int* in_sizes, int n_in,
                              void* d_out, int out_size, void* d_ws, size_t ws_size,
                              hipStream_t stream) {
    const float* nn = (const float*)d_in[0];
    const float* kr = (const float*)d_in[1];
    const float* ki = (const float*)d_in[2];
    const int* bsz = (const int*)d_in[3];
    float* ws = (float*)d_ws;
    float* out = (float*)d_out;
    int B = in_sizes[0] / SROW;

    int nz = GOFF + B * 2 * NPAIR * 2;
    hipLaunchKernelGGL(init_ws_kernel, dim3((nz + 255) / 256), dim3(256), 0, stream, ws, nz);
    hipLaunchKernelGGL(gram_kernel, dim3(B * 2 * 8), dim3(256), 0, stream, nn, ws);
    hipLaunchKernelGGL(absred_kernel, dim3(B * 2), dim3(256), 0, stream, ws);
    hipLaunchKernelGGL(main_kernel, dim3(E / TILE, E / TILE, B), dim3(256), 0, stream,
                       nn, kr, ki, ws);
    hipLaunchKernelGGL(fin_kernel, dim3(1), dim3(64), 0, stream, ws, bsz, out);
}